// Round 3
// baseline (1299.350 us; speedup 1.0000x reference)
//
#include <hip/hip_runtime.h>
#include <hip/hip_bf16.h>
#include <cstdint>
#include <cstddef>

#define BATCH 8192
#define INSZ 4096
#define HID 4096
#define NCLS 10

typedef __bf16 bf16_t;
typedef bf16_t bf16x8 __attribute__((ext_vector_type(8)));
typedef bf16_t bf16x4 __attribute__((ext_vector_type(4)));
typedef float f32x4 __attribute__((ext_vector_type(4)));

// Async global->LDS, 16B per lane. LDS dest is wave-uniform base + lane*16;
// passing (base + tid*16) works because HW reads the base from the first lane.
__device__ __forceinline__ void async_copy16(const void* g, void* l) {
  __builtin_amdgcn_global_load_lds(
      (const __attribute__((address_space(1))) void*)g,
      (__attribute__((address_space(3))) void*)l, 16, 0, 0);
}

__device__ __forceinline__ float signf(float x) {
  return (x > 0.f) ? 1.f : ((x < 0.f) ? -1.f : 0.f);
}

// f32 -> bf16 sign cast, vectorized 4-wide (16B load / 8B store per thread).
__global__ __launch_bounds__(256)
void sign_cast_f32_bf16(const float* __restrict__ in, bf16_t* __restrict__ out, int n4) {
  int i = blockIdx.x * blockDim.x + threadIdx.x;
  if (i >= n4) return;
  f32x4 v = ((const f32x4*)in)[i];
  bf16x4 s;
#pragma unroll
  for (int j = 0; j < 4; ++j) s[j] = (bf16_t)signf(v[j]);
  ((bf16x4*)out)[i] = s;
}

// C = sign(A @ B^T). A:[M][K], B:[N][K] (i.e. W as given), C:[M][N], all bf16.
// m97 structure: 128x128 tile, BK=32, 4 waves in 2x2, 4x4 16x16x32 MFMA frags,
// global_load_lds width-16 staging, single barrier pair per K-step.
// T1: XCD-aware bijective blockIdx swizzle (grid 2048 % 8 == 0).
__global__ __launch_bounds__(256, 2)
void gemm_bt_sign(const bf16_t* __restrict__ A, const bf16_t* __restrict__ B,
                  bf16_t* __restrict__ C, int M, int N, int K) {
  constexpr int BM = 128, BN = 128, BK = 32;
  constexpr int NXCD = 8;
  __shared__ bf16_t As[BM * BK];  // 8 KiB
  __shared__ bf16_t Bs[BN * BK];  // 8 KiB

  const int nbn = N / BN;
  const int nwg = gridDim.x;
  // bijective since nwg % 8 == 0 (2048 here): chunk-per-XCD remap
  const int cpx = nwg / NXCD;
  const int bid = (blockIdx.x % NXCD) * cpx + blockIdx.x / NXCD;
  const int bm = bid / nbn;
  const int bn = bid % nbn;

  const int tid = threadIdx.x;
  const int lane = tid & 63;
  const int wave = tid >> 6;
  const int wr = wave >> 1;  // wave row (0..1) -> 64 rows each
  const int wc = wave & 1;   // wave col (0..1) -> 64 cols each

  const bf16_t* Ablk = A + (size_t)bm * BM * K;
  const bf16_t* Bblk = B + (size_t)bn * BN * K;

  // staging: thread t covers row (j*64 + t/4), elements [(t%4)*8 .. +8)
  const int srow = tid >> 2;
  const int scol = (tid & 3) * 8;

  // fragment addressing: row/col = lane&15, k-offset = (lane>>4)*8
  const int rf = lane & 15;
  const int kf = (lane >> 4) * 8;

  f32x4 acc[4][4];
#pragma unroll
  for (int m = 0; m < 4; ++m)
#pragma unroll
    for (int n = 0; n < 4; ++n) acc[m][n] = (f32x4){0.f, 0.f, 0.f, 0.f};

  for (int k0 = 0; k0 < K; k0 += BK) {
#pragma unroll
    for (int j = 0; j < 2; ++j) {
      async_copy16(Ablk + (size_t)(j * 64 + srow) * K + (k0 + scol),
                   (char*)As + j * 4096 + tid * 16);
      async_copy16(Bblk + (size_t)(j * 64 + srow) * K + (k0 + scol),
                   (char*)Bs + j * 4096 + tid * 16);
    }
    __syncthreads();  // compiler emits vmcnt(0) drain before barrier

    bf16x8 af[4], bfr[4];
#pragma unroll
    for (int m = 0; m < 4; ++m)
      af[m] = *(const bf16x8*)(As + (wr * 64 + m * 16 + rf) * BK + kf);
#pragma unroll
    for (int n = 0; n < 4; ++n)
      bfr[n] = *(const bf16x8*)(Bs + (wc * 64 + n * 16 + rf) * BK + kf);

#pragma unroll
    for (int m = 0; m < 4; ++m)
#pragma unroll
      for (int n = 0; n < 4; ++n)
        acc[m][n] = __builtin_amdgcn_mfma_f32_16x16x32_bf16(af[m], bfr[n], acc[m][n], 0, 0, 0);

    __syncthreads();
  }

  // Epilogue: fused sign, C/D mapping col=lane&15, row=(lane>>4)*4+reg (m89-verified)
  bf16_t* Cblk = C + (size_t)(bm * BM) * N + bn * BN;
  const int ch = lane >> 4;
#pragma unroll
  for (int m = 0; m < 4; ++m)
#pragma unroll
    for (int n = 0; n < 4; ++n)
#pragma unroll
      for (int r = 0; r < 4; ++r) {
        float v = acc[m][n][r];
        Cblk[(size_t)(wr * 64 + m * 16 + ch * 4 + r) * N + (wc * 64 + n * 16 + rf)] =
            (bf16_t)signf(v);
      }
}

// Last layer: [8192x4096] bf16 x [10x4096] bf16 -> sign -> [8192x10] f32.
// One wave per output row; lane-parallel over K, shuffle reduce.
__global__ __launch_bounds__(256)
void final_layer(const bf16_t* __restrict__ A, const bf16_t* __restrict__ W,
                 float* __restrict__ out) {
  const int lane = threadIdx.x & 63;
  const int wave = threadIdx.x >> 6;
  const int row = blockIdx.x * 4 + wave;
  const bf16_t* a = A + (size_t)row * HID;

  float acc[NCLS];
#pragma unroll
  for (int n = 0; n < NCLS; ++n) acc[n] = 0.f;

#pragma unroll
  for (int c = 0; c < HID / 512; ++c) {
    const int k = c * 512 + lane * 8;
    bf16x8 av = *(const bf16x8*)(a + k);
#pragma unroll
    for (int n = 0; n < NCLS; ++n) {
      bf16x8 wv = *(const bf16x8*)(W + (size_t)n * HID + k);
      float s = 0.f;
#pragma unroll
      for (int j = 0; j < 8; ++j) s += (float)av[j] * (float)wv[j];
      acc[n] += s;
    }
  }

#pragma unroll
  for (int n = 0; n < NCLS; ++n) {
    float v = acc[n];
#pragma unroll
    for (int off = 32; off > 0; off >>= 1) v += __shfl_xor(v, off, 64);
    if (lane == 0) out[(size_t)row * NCLS + n] = signf(v);
  }
}

extern "C" void kernel_launch(void* const* d_in, const int* in_sizes, int n_in,
                              void* d_out, int out_size, void* d_ws, size_t ws_size,
                              hipStream_t stream) {
  const float* x  = (const float*)d_in[0];
  const float* W0 = (const float*)d_in[1];
  const float* W1 = (const float*)d_in[2];
  const float* W2 = (const float*)d_in[3];
  const float* W3 = (const float*)d_in[4];
  float* out = (float*)d_out;

  // Workspace layout (needs 160 MiB + 80 KiB):
  //   actA  [8192*4096] bf16 = 64 MiB
  //   actB  [8192*4096] bf16 = 64 MiB
  //   wbuf  [4096*4096] bf16 = 32 MiB  (reused per layer)
  //   w3buf [10*4096]   bf16
  char* ws = (char*)d_ws;
  bf16_t* actA  = (bf16_t*)ws;
  bf16_t* actB  = (bf16_t*)(ws + (size_t)BATCH * HID * 2);
  bf16_t* wbuf  = (bf16_t*)(ws + (size_t)2 * BATCH * HID * 2);
  bf16_t* w3buf = (bf16_t*)(ws + (size_t)2 * BATCH * HID * 2 + (size_t)HID * HID * 2);

  dim3 blk(256);
  const int gemm_grid = (BATCH / 128) * (HID / 128);  // 2048

  const int n4x = BATCH * INSZ / 4;
  sign_cast_f32_bf16<<<(n4x + 255) / 256, blk, 0, stream>>>(x, actA, n4x);

  const int n4w = HID * INSZ / 4;
  sign_cast_f32_bf16<<<(n4w + 255) / 256, blk, 0, stream>>>(W0, wbuf, n4w);
  gemm_bt_sign<<<gemm_grid, blk, 0, stream>>>(actA, wbuf, actB, BATCH, HID, INSZ);

  sign_cast_f32_bf16<<<(n4w + 255) / 256, blk, 0, stream>>>(W1, wbuf, n4w);
  gemm_bt_sign<<<gemm_grid, blk, 0, stream>>>(actB, wbuf, actA, BATCH, HID, HID);

  sign_cast_f32_bf16<<<(n4w + 255) / 256, blk, 0, stream>>>(W2, wbuf, n4w);
  gemm_bt_sign<<<gemm_grid, blk, 0, stream>>>(actA, wbuf, actB, BATCH, HID, HID);

  const int n4w3 = NCLS * HID / 4;
  sign_cast_f32_bf16<<<(n4w3 + 255) / 256, blk, 0, stream>>>(W3, w3buf, n4w3);
  final_layer<<<BATCH / 4, blk, 0, stream>>>(actB, w3buf, out);
}

// Round 4
// 1043.509 us; speedup vs baseline: 1.2452x; 1.2452x over previous
//
#include <hip/hip_runtime.h>
#include <hip/hip_bf16.h>
#include <cstdint>
#include <cstddef>

#define BATCH 8192
#define INSZ 4096
#define HID 4096
#define NCLS 10

typedef __bf16 bf16_t;
typedef bf16_t bf16x8 __attribute__((ext_vector_type(8)));
typedef bf16_t bf16x4 __attribute__((ext_vector_type(4)));
typedef float f32x4 __attribute__((ext_vector_type(4)));

__device__ __forceinline__ void async_copy16(const void* g, void* l) {
  __builtin_amdgcn_global_load_lds(
      (const __attribute__((address_space(1))) void*)g,
      (__attribute__((address_space(3))) void*)l, 16, 0, 0);
}

__device__ __forceinline__ float signf(float x) {
  return (x > 0.f) ? 1.f : ((x < 0.f) ? -1.f : 0.f);
}

// f32 -> bf16 sign cast, vectorized 4-wide.
__global__ __launch_bounds__(256)
void sign_cast_f32_bf16(const float* __restrict__ in, bf16_t* __restrict__ out, int n4) {
  int i = blockIdx.x * blockDim.x + threadIdx.x;
  if (i >= n4) return;
  f32x4 v = ((const f32x4*)in)[i];
  bf16x4 s;
#pragma unroll
  for (int j = 0; j < 4; ++j) s[j] = (bf16_t)signf(v[j]);
  ((bf16x4*)out)[i] = s;
}

// ---------------------------------------------------------------------------
// 256x256 8-phase GEMM: C = sign(A @ B^T), A:[M][K], B:[N][K], C:[M][N] bf16.
// 8 waves (2M x 4N), BK=64, 2 LDS buffers x (A 32K + B 32K) = 128 KiB.
// Phase order per K-tile: (qm,qn) = (0,0),(0,1),(1,1),(1,0).
// Stage schedule: p1: T(k+1).B0 -> other buf   (B0 region freed end of prev block)
//                 p2: T(k+1).A1 -> other buf   (A1 freed end of prev block)
//                 p3: T(k+2).A0 -> current buf (A0 freed after p2)
//                 p4: T(k+2).B1 -> current buf (B1 freed after p3)
// Boundary: vmcnt(4) retires exactly T(k+1)'s 4 halves, leaves T(k+2).{A0,B1}
// in flight. LDS swizzle: byte ^= ((row&7)<<4), applied via pre-swizzled
// global source (src16 = lane ^ (lane>>3)) + swizzled ds_read address.
// ---------------------------------------------------------------------------

#define MMA_QUAD(QM, QN)                                                      \
  do {                                                                        \
    _Pragma("unroll") for (int m4 = 0; m4 < 4; ++m4) {                        \
      _Pragma("unroll") for (int n2 = 0; n2 < 2; ++n2) {                      \
        acc[(QM)*4 + m4][(QN)*2 + n2] = __builtin_amdgcn_mfma_f32_16x16x32_bf16( \
            af[m4][0], bfr[n2][0], acc[(QM)*4 + m4][(QN)*2 + n2], 0, 0, 0);   \
        acc[(QM)*4 + m4][(QN)*2 + n2] = __builtin_amdgcn_mfma_f32_16x16x32_bf16( \
            af[m4][1], bfr[n2][1], acc[(QM)*4 + m4][(QN)*2 + n2], 0, 0, 0);   \
      }                                                                       \
    }                                                                         \
  } while (0)

#define LDA_HALF(BUFA)                                                        \
  do {                                                                        \
    _Pragma("unroll") for (int m4 = 0; m4 < 4; ++m4) {                        \
      af[m4][0] = *(const bf16x8*)((BUFA) + m4 * 4096 + aRowB + c0);          \
      af[m4][1] = *(const bf16x8*)((BUFA) + m4 * 4096 + aRowB + c1);          \
    }                                                                         \
  } while (0)

#define LDB_HALF(BUFB)                                                        \
  do {                                                                        \
    _Pragma("unroll") for (int n2 = 0; n2 < 2; ++n2) {                        \
      bfr[n2][0] = *(const bf16x8*)((BUFB) + n2 * 8192 + bRowB + c0);         \
      bfr[n2][1] = *(const bf16x8*)((BUFB) + n2 * 8192 + bRowB + c1);         \
    }                                                                         \
  } while (0)

#define STAGE(GBASE, LHALF, TCOL)                                             \
  do {                                                                        \
    async_copy16((GBASE) + (TCOL), (LHALF) + dst0);                           \
    async_copy16((GBASE) + jstride + (TCOL), (LHALF) + dst0 + 8192);          \
  } while (0)

#define BAR() __builtin_amdgcn_s_barrier()

__global__ __launch_bounds__(512, 2)
void gemm256_bt_sign(const bf16_t* __restrict__ A, const bf16_t* __restrict__ B,
                     bf16_t* __restrict__ C, int M, int N, int K) {
  constexpr int BM = 256, BN = 256, BK = 64;
  constexpr int NXCD = 8;
  // buf layout: [A0: 0,16K) [A1: 16K,32K) [B0: 32K,48K) [B1: 48K,64K)
  __shared__ char lds[2][65536];

  const int nbn = N / BN;
  const int nwg = gridDim.x;
  const int cpx = nwg / NXCD;  // grids here are multiples of 8 -> bijective
  const int bid = (blockIdx.x % NXCD) * cpx + blockIdx.x / NXCD;
  const int bm = bid / nbn, bn = bid % nbn;

  const int tid = threadIdx.x;
  const int lane = tid & 63;
  const int w = tid >> 6;   // wave 0..7
  const int wr = w >> 2;    // 0..1 (M split)
  const int wc = w & 3;     // 0..3 (N split)

  // ---- staging constants (pre-swizzled global source) ----
  const int src16 = lane ^ (lane >> 3);        // involution on 16B chunks
  const int srow0 = w * 8 + (src16 >> 3);      // row in half-tile, j=0
  const int scol  = (src16 & 7) * 8;           // element col in [0,64)
  const bf16_t* aBase0 = A + (size_t)(bm * BM + srow0) * K + scol;
  const bf16_t* aBase1 = A + (size_t)(bm * BM + 128 + srow0) * K + scol;
  const bf16_t* bBase0 = B + (size_t)(bn * BN + srow0) * K + scol;
  const bf16_t* bBase1 = B + (size_t)(bn * BN + 128 + srow0) * K + scol;
  const size_t jstride = (size_t)64 * K;       // second 64 rows of a half
  const int dst0 = w * 1024 + lane * 16;       // linear LDS dest within half

  // ---- ds_read constants (swizzled read addresses) ----
  const int rf = lane & 15;
  const int c0 = ((lane >> 4) * 16) ^ ((lane & 7) << 4);        // kk=0
  const int c1 = (64 + (lane >> 4) * 16) ^ ((lane & 7) << 4);   // kk=1
  const int aRowB = (wr * 16 + rf) * 128;
  const int bRowB = (wc * 16 + rf) * 128;

  f32x4 acc[8][4];
#pragma unroll
  for (int m = 0; m < 8; ++m)
#pragma unroll
    for (int n = 0; n < 4; ++n) acc[m][n] = (f32x4){0.f, 0.f, 0.f, 0.f};

  bf16x8 af[4][2];   // A frags of current qm
  bf16x8 bfr[2][2];  // B frags of current qn

  const int NT = K / BK;  // 64

  // ---- prologue: T0 all 4 halves -> buf0; T1.A0, T1.B1 -> buf1 ----
  STAGE(aBase0, lds[0] + 0,     0);
  STAGE(bBase0, lds[0] + 32768, 0);
  STAGE(bBase1, lds[0] + 49152, 0);
  STAGE(aBase1, lds[0] + 16384, 0);
  STAGE(aBase0, lds[1] + 0,     BK);
  STAGE(bBase1, lds[1] + 49152, BK);
  asm volatile("s_waitcnt vmcnt(4)" ::: "memory");  // T0 landed; T1 pair in flight
  BAR();

  for (int k = 0; k < NT; ++k) {
    char* bufc = lds[k & 1];
    char* bufo = lds[(k & 1) ^ 1];
    const int t1 = (k + 1) * BK, t2 = (k + 2) * BK;
    const bool s1 = (k + 1 < NT), s2 = (k + 2 < NT);

    // ---- p1: quadrant (0,0) ----
    LDA_HALF(bufc + 0);
    LDB_HALF(bufc + 32768);
    if (s1) STAGE(bBase0, bufo + 32768, t1);
    BAR();
    __builtin_amdgcn_s_setprio(1);
    MMA_QUAD(0, 0);
    __builtin_amdgcn_s_setprio(0);
    BAR();

    // ---- p2: quadrant (0,1) (reuse af) ----
    LDB_HALF(bufc + 49152);
    if (s1) STAGE(aBase1, bufo + 16384, t1);
    BAR();
    __builtin_amdgcn_s_setprio(1);
    MMA_QUAD(0, 1);
    __builtin_amdgcn_s_setprio(0);
    BAR();

    // ---- p3: quadrant (1,1) (reuse bfr) ----
    LDA_HALF(bufc + 16384);
    if (s2) STAGE(aBase0, bufc + 0, t2);     // A0 region freed after p2
    BAR();
    __builtin_amdgcn_s_setprio(1);
    MMA_QUAD(1, 1);
    __builtin_amdgcn_s_setprio(0);
    BAR();

    // ---- p4: quadrant (1,0) (reuse af) ----
    LDB_HALF(bufc + 32768);
    if (s2) STAGE(bBase1, bufc + 49152, t2); // B1 region freed after p3
    BAR();
    __builtin_amdgcn_s_setprio(1);
    MMA_QUAD(1, 0);
    __builtin_amdgcn_s_setprio(0);
    // ---- block boundary: counted wait gating next block's reads ----
    if (k < NT - 1) {
      if (k <= NT - 3)
        asm volatile("s_waitcnt vmcnt(4)" ::: "memory");  // T(k+1) retired
      else
        asm volatile("s_waitcnt vmcnt(0)" ::: "memory");  // tail drain
    }
    BAR();
  }

  // ---- epilogue: fused sign, C/D mapping col=lane&15, row=(lane>>4)*4+r ----
  const int ch = lane >> 4;
#pragma unroll
  for (int m = 0; m < 8; ++m) {
    const int qm = m >> 2, m4 = m & 3;
#pragma unroll
    for (int n = 0; n < 4; ++n) {
      const int qn = n >> 1, n2 = n & 1;
#pragma unroll
      for (int r = 0; r < 4; ++r) {
        float v = acc[m][n][r];
        C[(size_t)(bm * BM + qm * 128 + m4 * 32 + wr * 16 + ch * 4 + r) * N +
          (bn * BN + qn * 128 + n2 * 64 + wc * 16 + rf)] = (bf16_t)signf(v);
      }
    }
  }
}

// Last layer: [8192x4096] x [10x4096]^T -> sign -> [8192x10] f32.
__global__ __launch_bounds__(256)
void final_layer(const bf16_t* __restrict__ A, const bf16_t* __restrict__ W,
                 float* __restrict__ out) {
  const int lane = threadIdx.x & 63;
  const int wave = threadIdx.x >> 6;
  const int row = blockIdx.x * 4 + wave;
  const bf16_t* a = A + (size_t)row * HID;

  float acc[NCLS];
#pragma unroll
  for (int n = 0; n < NCLS; ++n) acc[n] = 0.f;

#pragma unroll
  for (int c = 0; c < HID / 512; ++c) {
    const int k = c * 512 + lane * 8;
    bf16x8 av = *(const bf16x8*)(a + k);
#pragma unroll
    for (int n = 0; n < NCLS; ++n) {
      bf16x8 wv = *(const bf16x8*)(W + (size_t)n * HID + k);
      float s = 0.f;
#pragma unroll
      for (int j = 0; j < 8; ++j) s += (float)av[j] * (float)wv[j];
      acc[n] += s;
    }
  }

#pragma unroll
  for (int n = 0; n < NCLS; ++n) {
    float v = acc[n];
#pragma unroll
    for (int off = 32; off > 0; off >>= 1) v += __shfl_xor(v, off, 64);
    if (lane == 0) out[(size_t)row * NCLS + n] = signf(v);
  }
}

extern "C" void kernel_launch(void* const* d_in, const int* in_sizes, int n_in,
                              void* d_out, int out_size, void* d_ws, size_t ws_size,
                              hipStream_t stream) {
  const float* x  = (const float*)d_in[0];
  const float* W0 = (const float*)d_in[1];
  const float* W1 = (const float*)d_in[2];
  const float* W2 = (const float*)d_in[3];
  const float* W3 = (const float*)d_in[4];
  float* out = (float*)d_out;

  char* ws = (char*)d_ws;
  bf16_t* actA  = (bf16_t*)ws;
  bf16_t* actB  = (bf16_t*)(ws + (size_t)BATCH * HID * 2);
  bf16_t* wbuf  = (bf16_t*)(ws + (size_t)2 * BATCH * HID * 2);
  bf16_t* w3buf = (bf16_t*)(ws + (size_t)2 * BATCH * HID * 2 + (size_t)HID * HID * 2);

  dim3 blk(256);
  const int gemm_grid = (BATCH / 256) * (HID / 256);  // 512, % 8 == 0

  const int n4x = BATCH * INSZ / 4;
  sign_cast_f32_bf16<<<(n4x + 255) / 256, blk, 0, stream>>>(x, actA, n4x);

  const int n4w = HID * INSZ / 4;
  sign_cast_f32_bf16<<<(n4w + 255) / 256, blk, 0, stream>>>(W0, wbuf, n4w);
  gemm256_bt_sign<<<gemm_grid, dim3(512), 0, stream>>>(actA, wbuf, actB, BATCH, HID, INSZ);

  sign_cast_f32_bf16<<<(n4w + 255) / 256, blk, 0, stream>>>(W1, wbuf, n4w);
  gemm256_bt_sign<<<gemm_grid, dim3(512), 0, stream>>>(actB, wbuf, actA, BATCH, HID, HID);

  sign_cast_f32_bf16<<<(n4w + 255) / 256, blk, 0, stream>>>(W2, wbuf, n4w);
  gemm256_bt_sign<<<gemm_grid, dim3(512), 0, stream>>>(actA, wbuf, actB, BATCH, HID, HID);

  const int n4w3 = NCLS * HID / 4;
  sign_cast_f32_bf16<<<(n4w3 + 255) / 256, blk, 0, stream>>>(W3, w3buf, n4w3);
  final_layer<<<BATCH / 4, blk, 0, stream>>>(actB, w3buf, out);
}

// Round 5
// 710.550 us; speedup vs baseline: 1.8287x; 1.4686x over previous
//
#include <hip/hip_runtime.h>
#include <hip/hip_bf16.h>
#include <cstdint>
#include <cstddef>

#define BATCH 8192
#define INSZ 4096
#define HID 4096
#define NCLS 10

typedef float f32x4 __attribute__((ext_vector_type(4)));
typedef int i32x4 __attribute__((ext_vector_type(4)));
typedef char i8x4 __attribute__((ext_vector_type(4)));
typedef char i8x16 __attribute__((ext_vector_type(16)));

__device__ __forceinline__ void async_copy16(const void* g, void* l) {
  __builtin_amdgcn_global_load_lds(
      (const __attribute__((address_space(1))) void*)g,
      (__attribute__((address_space(3))) void*)l, 16, 0, 0);
}

// f32 -> i8 sign cast, 4-wide (16B load / 4B store per thread).
__global__ __launch_bounds__(256)
void sign_cast_f32_i8(const float* __restrict__ in, int8_t* __restrict__ out, int n4) {
  int i = blockIdx.x * blockDim.x + threadIdx.x;
  if (i >= n4) return;
  f32x4 v = ((const f32x4*)in)[i];
  i8x4 s;
#pragma unroll
  for (int j = 0; j < 4; ++j) s[j] = (char)((v[j] > 0.f) - (v[j] < 0.f));
  ((i8x4*)out)[i] = s;
}

// ---------------------------------------------------------------------------
// 256x256 8-phase i8 GEMM: C = sign(A @ B^T), A:[M][K], B:[N][K], C:[M][N] i8.
// Same byte-level schedule as the verified bf16 round-4 kernel (rows = 128 B,
// half-tile = 16 KiB, st-XOR swizzle byte^=((row&7)<<4) via pre-swizzled
// source + swizzled read). BK = 128 i8 elems; mfma_i32_16x16x64_i8; NT = K/128.
// Stage schedule / counted vmcnt(4) boundary identical to round 4.
// ---------------------------------------------------------------------------

#define MMA_QUAD(QM, QN)                                                      \
  do {                                                                        \
    _Pragma("unroll") for (int m4 = 0; m4 < 4; ++m4) {                        \
      _Pragma("unroll") for (int n2 = 0; n2 < 2; ++n2) {                      \
        acc[(QM)*4 + m4][(QN)*2 + n2] = __builtin_amdgcn_mfma_i32_16x16x64_i8( \
            af[m4][0], bfr[n2][0], acc[(QM)*4 + m4][(QN)*2 + n2], 0, 0, 0);   \
        acc[(QM)*4 + m4][(QN)*2 + n2] = __builtin_amdgcn_mfma_i32_16x16x64_i8( \
            af[m4][1], bfr[n2][1], acc[(QM)*4 + m4][(QN)*2 + n2], 0, 0, 0);   \
      }                                                                       \
    }                                                                         \
  } while (0)

#define LDA_HALF(BUFA)                                                        \
  do {                                                                        \
    _Pragma("unroll") for (int m4 = 0; m4 < 4; ++m4) {                        \
      af[m4][0] = *(const i32x4*)((BUFA) + m4 * 4096 + aRowB + c0);           \
      af[m4][1] = *(const i32x4*)((BUFA) + m4 * 4096 + aRowB + c1);           \
    }                                                                         \
  } while (0)

#define LDB_HALF(BUFB)                                                        \
  do {                                                                        \
    _Pragma("unroll") for (int n2 = 0; n2 < 2; ++n2) {                        \
      bfr[n2][0] = *(const i32x4*)((BUFB) + n2 * 8192 + bRowB + c0);          \
      bfr[n2][1] = *(const i32x4*)((BUFB) + n2 * 8192 + bRowB + c1);          \
    }                                                                         \
  } while (0)

#define STAGE(GBASE, LHALF, TCOL)                                             \
  do {                                                                        \
    async_copy16((GBASE) + (TCOL), (LHALF) + dst0);                           \
    async_copy16((GBASE) + jstride + (TCOL), (LHALF) + dst0 + 8192);          \
  } while (0)

#define BAR() __builtin_amdgcn_s_barrier()

__global__ __launch_bounds__(512, 2)
void gemm256_i8_sign(const int8_t* __restrict__ A, const int8_t* __restrict__ B,
                     int8_t* __restrict__ C, int M, int N, int K) {
  constexpr int BM = 256, BN = 256, BK = 128;  // BK in i8 elems = 128 B rows
  constexpr int NXCD = 8;
  // buf layout: [A0: 0,16K) [A1: 16K,32K) [B0: 32K,48K) [B1: 48K,64K)
  __shared__ char lds[2][65536];

  const int nbn = N / BN;
  const int nwg = gridDim.x;
  const int cpx = nwg / NXCD;  // grid 512 % 8 == 0 -> bijective
  const int bid = (blockIdx.x % NXCD) * cpx + blockIdx.x / NXCD;
  const int bm = bid / nbn, bn = bid % nbn;

  const int tid = threadIdx.x;
  const int lane = tid & 63;
  const int w = tid >> 6;
  const int wr = w >> 2;    // 0..1 (M split at 16-row granularity)
  const int wc = w & 3;     // 0..3 (N split)

  // ---- staging (pre-swizzled global source; bytes identical to bf16 ver) ----
  const int src16 = lane ^ (lane >> 3);
  const int srow0 = w * 8 + (src16 >> 3);
  const int scol  = (src16 & 7) * 16;          // i8 elems (= bytes)
  const int8_t* aBase0 = A + (size_t)(bm * BM + srow0) * K + scol;
  const int8_t* aBase1 = A + (size_t)(bm * BM + 128 + srow0) * K + scol;
  const int8_t* bBase0 = B + (size_t)(bn * BN + srow0) * K + scol;
  const int8_t* bBase1 = B + (size_t)(bn * BN + 128 + srow0) * K + scol;
  const size_t jstride = (size_t)64 * K;
  const int dst0 = w * 1024 + lane * 16;

  // ---- ds_read constants (swizzled byte addresses; identical to bf16) ----
  const int rf = lane & 15;
  const int c0 = ((lane >> 4) * 16) ^ ((lane & 7) << 4);        // kstep 0 (K 0..63)
  const int c1 = (64 + (lane >> 4) * 16) ^ ((lane & 7) << 4);   // kstep 1 (K 64..127)
  const int aRowB = (wr * 16 + rf) * 128;
  const int bRowB = (wc * 16 + rf) * 128;

  i32x4 acc[8][4];
#pragma unroll
  for (int m = 0; m < 8; ++m)
#pragma unroll
    for (int n = 0; n < 4; ++n) acc[m][n] = (i32x4){0, 0, 0, 0};

  i32x4 af[4][2];
  i32x4 bfr[2][2];

  const int NT = K / BK;  // 32

  // ---- prologue: T0 all 4 halves -> buf0; T1.A0, T1.B1 -> buf1 ----
  STAGE(aBase0, lds[0] + 0,     0);
  STAGE(bBase0, lds[0] + 32768, 0);
  STAGE(bBase1, lds[0] + 49152, 0);
  STAGE(aBase1, lds[0] + 16384, 0);
  STAGE(aBase0, lds[1] + 0,     BK);
  STAGE(bBase1, lds[1] + 49152, BK);
  asm volatile("s_waitcnt vmcnt(4)" ::: "memory");
  BAR();

  for (int k = 0; k < NT; ++k) {
    char* bufc = lds[k & 1];
    char* bufo = lds[(k & 1) ^ 1];
    const int t1 = (k + 1) * BK, t2 = (k + 2) * BK;
    const bool s1 = (k + 1 < NT), s2 = (k + 2 < NT);

    // ---- p1: quadrant (0,0) ----
    LDA_HALF(bufc + 0);
    LDB_HALF(bufc + 32768);
    if (s1) STAGE(bBase0, bufo + 32768, t1);
    BAR();
    __builtin_amdgcn_s_setprio(1);
    MMA_QUAD(0, 0);
    __builtin_amdgcn_s_setprio(0);
    BAR();

    // ---- p2: quadrant (0,1) ----
    LDB_HALF(bufc + 49152);
    if (s1) STAGE(aBase1, bufo + 16384, t1);
    BAR();
    __builtin_amdgcn_s_setprio(1);
    MMA_QUAD(0, 1);
    __builtin_amdgcn_s_setprio(0);
    BAR();

    // ---- p3: quadrant (1,1) ----
    LDA_HALF(bufc + 16384);
    if (s2) STAGE(aBase0, bufc + 0, t2);
    BAR();
    __builtin_amdgcn_s_setprio(1);
    MMA_QUAD(1, 1);
    __builtin_amdgcn_s_setprio(0);
    BAR();

    // ---- p4: quadrant (1,0) ----
    LDB_HALF(bufc + 32768);
    if (s2) STAGE(bBase1, bufc + 49152, t2);
    BAR();
    __builtin_amdgcn_s_setprio(1);
    MMA_QUAD(1, 0);
    __builtin_amdgcn_s_setprio(0);
    if (k < NT - 1) {
      if (k <= NT - 3)
        asm volatile("s_waitcnt vmcnt(4)" ::: "memory");  // T(k+1) retired
      else
        asm volatile("s_waitcnt vmcnt(0)" ::: "memory");  // tail drain
    }
    BAR();
  }

  // ---- epilogue: integer sign, C/D mapping col=lane&15, row=(lane>>4)*4+r ----
  const int ch = lane >> 4;
#pragma unroll
  for (int m = 0; m < 8; ++m) {
    const int qm = m >> 2, m4 = m & 3;
#pragma unroll
    for (int n = 0; n < 4; ++n) {
      const int qn = n >> 1, n2 = n & 1;
#pragma unroll
      for (int r = 0; r < 4; ++r) {
        int v = acc[m][n][r];
        C[(size_t)(bm * BM + qm * 128 + m4 * 32 + wr * 16 + ch * 4 + r) * N +
          (bn * BN + qn * 128 + n2 * 64 + wc * 16 + rf)] = (int8_t)((v > 0) - (v < 0));
      }
    }
  }
}

// Last layer: [8192x4096] i8 x [10x4096] i8^T -> sign -> [8192x10] f32.
__global__ __launch_bounds__(256)
void final_layer_i8(const int8_t* __restrict__ A, const int8_t* __restrict__ W,
                    float* __restrict__ out) {
  const int lane = threadIdx.x & 63;
  const int wave = threadIdx.x >> 6;
  const int row = blockIdx.x * 4 + wave;
  const int8_t* a = A + (size_t)row * HID;

  int acc[NCLS];
#pragma unroll
  for (int n = 0; n < NCLS; ++n) acc[n] = 0;

#pragma unroll
  for (int c = 0; c < HID / 1024; ++c) {   // 4 chunks of 16 i8/lane
    const int k = c * 1024 + lane * 16;
    i8x16 av = *(const i8x16*)(a + k);
#pragma unroll
    for (int n = 0; n < NCLS; ++n) {
      i8x16 wv = *(const i8x16*)(W + (size_t)n * HID + k);
      int s = 0;
#pragma unroll
      for (int j = 0; j < 16; ++j) s += (int)av[j] * (int)wv[j];
      acc[n] += s;
    }
  }

#pragma unroll
  for (int n = 0; n < NCLS; ++n) {
    int v = acc[n];
#pragma unroll
    for (int off = 32; off > 0; off >>= 1) v += __shfl_xor(v, off, 64);
    if (lane == 0) out[(size_t)row * NCLS + n] = (float)((v > 0) - (v < 0));
  }
}

extern "C" void kernel_launch(void* const* d_in, const int* in_sizes, int n_in,
                              void* d_out, int out_size, void* d_ws, size_t ws_size,
                              hipStream_t stream) {
  const float* x  = (const float*)d_in[0];
  const float* W0 = (const float*)d_in[1];
  const float* W1 = (const float*)d_in[2];
  const float* W2 = (const float*)d_in[3];
  const float* W3 = (const float*)d_in[4];
  float* out = (float*)d_out;

  // Workspace: actA 32MB, actB 32MB, wbuf 16MB, w3buf 40KB  (~80 MiB)
  char* ws = (char*)d_ws;
  int8_t* actA  = (int8_t*)ws;
  int8_t* actB  = (int8_t*)(ws + (size_t)BATCH * HID);
  int8_t* wbuf  = (int8_t*)(ws + (size_t)2 * BATCH * HID);
  int8_t* w3buf = (int8_t*)(ws + (size_t)2 * BATCH * HID + (size_t)HID * HID);

  dim3 blk(256);
  const int gemm_grid = (BATCH / 256) * (HID / 256);  // 512, % 8 == 0

  const int n4x = BATCH * INSZ / 4;
  sign_cast_f32_i8<<<(n4x + 255) / 256, blk, 0, stream>>>(x, actA, n4x);

  const int n4w = HID * INSZ / 4;
  sign_cast_f32_i8<<<(n4w + 255) / 256, blk, 0, stream>>>(W0, wbuf, n4w);
  gemm256_i8_sign<<<gemm_grid, dim3(512), 0, stream>>>(actA, wbuf, actB, BATCH, HID, INSZ);

  sign_cast_f32_i8<<<(n4w + 255) / 256, blk, 0, stream>>>(W1, wbuf, n4w);
  gemm256_i8_sign<<<gemm_grid, dim3(512), 0, stream>>>(actB, wbuf, actA, BATCH, HID, HID);

  sign_cast_f32_i8<<<(n4w + 255) / 256, blk, 0, stream>>>(W2, wbuf, n4w);
  gemm256_i8_sign<<<gemm_grid, dim3(512), 0, stream>>>(actA, wbuf, actB, BATCH, HID, HID);

  const int n4w3 = NCLS * HID / 4;
  sign_cast_f32_i8<<<(n4w3 + 255) / 256, blk, 0, stream>>>(W3, w3buf, n4w3);
  final_layer_i8<<<BATCH / 4, blk, 0, stream>>>(actB, w3buf, out);
}

// Round 9
// 703.460 us; speedup vs baseline: 1.8471x; 1.0101x over previous
//
#include <hip/hip_runtime.h>
#include <hip/hip_bf16.h>
#include <cstdint>
#include <cstddef>

#define BATCH 8192
#define INSZ 4096
#define HID 4096
#define NCLS 10

typedef float f32x4 __attribute__((ext_vector_type(4)));
typedef int i32x4 __attribute__((ext_vector_type(4)));
typedef char i8x16 __attribute__((ext_vector_type(16)));

__device__ __forceinline__ void async_copy16(const void* g, void* l) {
  __builtin_amdgcn_global_load_lds(
      (const __attribute__((address_space(1))) void*)g,
      (__attribute__((address_space(3))) void*)l, 16, 0, 0);
}

// ---------------------------------------------------------------------------
// One fused sign-cast pass for ALL inputs: f32 -> i8 in {-1,0,+1}.
// Per thread: 4 x f32x4 loads (64 B) -> one i8x16 store (16 B sweet spot).
// Chunk ranges (16 f32 each): x 2097152 | W0..W2 1048576 each | W3 2560.
// All boundaries are multiples of 256 chunks -> blocks never straddle ranges.
// ---------------------------------------------------------------------------
__global__ __launch_bounds__(256)
void sign_cast_all(const float* __restrict__ x, const float* __restrict__ W0,
                   const float* __restrict__ W1, const float* __restrict__ W2,
                   const float* __restrict__ W3,
                   int8_t* __restrict__ actA, int8_t* __restrict__ wb0,
                   int8_t* __restrict__ wb1, int8_t* __restrict__ wb2,
                   int8_t* __restrict__ w3b) {
  constexpr int CX = 2097152;           // 8192*4096/16
  constexpr int CW = 1048576;           // 4096*4096/16
  const int c = blockIdx.x * blockDim.x + threadIdx.x;

  const float* src;
  int8_t* dst;
  int base;
  if (c < CX)               { src = x;  dst = actA; base = c; }
  else if (c < CX + CW)     { src = W0; dst = wb0;  base = c - CX; }
  else if (c < CX + 2 * CW) { src = W1; dst = wb1;  base = c - (CX + CW); }
  else if (c < CX + 3 * CW) { src = W2; dst = wb2;  base = c - (CX + 2 * CW); }
  else                      { src = W3; dst = w3b;  base = c - (CX + 3 * CW); }

  const f32x4* in4 = (const f32x4*)src + (size_t)base * 4;
  i8x16 s;
#pragma unroll
  for (int q = 0; q < 4; ++q) {
    f32x4 v = in4[q];
#pragma unroll
    for (int j = 0; j < 4; ++j) s[q * 4 + j] = (char)((v[j] > 0.f) - (v[j] < 0.f));
  }
  ((i8x16*)dst)[base] = s;
}

// ---------------------------------------------------------------------------
// 256x256 8-phase i8 GEMM (unchanged from round 5): C = sign(A @ B^T).
// ---------------------------------------------------------------------------

#define MMA_QUAD(QM, QN)                                                      \
  do {                                                                        \
    _Pragma("unroll") for (int m4 = 0; m4 < 4; ++m4) {                        \
      _Pragma("unroll") for (int n2 = 0; n2 < 2; ++n2) {                      \
        acc[(QM)*4 + m4][(QN)*2 + n2] = __builtin_amdgcn_mfma_i32_16x16x64_i8( \
            af[m4][0], bfr[n2][0], acc[(QM)*4 + m4][(QN)*2 + n2], 0, 0, 0);   \
        acc[(QM)*4 + m4][(QN)*2 + n2] = __builtin_amdgcn_mfma_i32_16x16x64_i8( \
            af[m4][1], bfr[n2][1], acc[(QM)*4 + m4][(QN)*2 + n2], 0, 0, 0);   \
      }                                                                       \
    }                                                                         \
  } while (0)

#define LDA_HALF(BUFA)                                                        \
  do {                                                                        \
    _Pragma("unroll") for (int m4 = 0; m4 < 4; ++m4) {                        \
      af[m4][0] = *(const i32x4*)((BUFA) + m4 * 4096 + aRowB + c0);           \
      af[m4][1] = *(const i32x4*)((BUFA) + m4 * 4096 + aRowB + c1);           \
    }                                                                         \
  } while (0)

#define LDB_HALF(BUFB)                                                        \
  do {                                                                        \
    _Pragma("unroll") for (int n2 = 0; n2 < 2; ++n2) {                        \
      bfr[n2][0] = *(const i32x4*)((BUFB) + n2 * 8192 + bRowB + c0);          \
      bfr[n2][1] = *(const i32x4*)((BUFB) + n2 * 8192 + bRowB + c1);          \
    }                                                                         \
  } while (0)

#define STAGE(GBASE, LHALF, TCOL)                                             \
  do {                                                                        \
    async_copy16((GBASE) + (TCOL), (LHALF) + dst0);                           \
    async_copy16((GBASE) + jstride + (TCOL), (LHALF) + dst0 + 8192);          \
  } while (0)

#define BAR() __builtin_amdgcn_s_barrier()

__global__ __launch_bounds__(512, 2)
void gemm256_i8_sign(const int8_t* __restrict__ A, const int8_t* __restrict__ B,
                     int8_t* __restrict__ C, int M, int N, int K) {
  constexpr int BM = 256, BN = 256, BK = 128;
  constexpr int NXCD = 8;
  __shared__ char lds[2][65536];

  const int nbn = N / BN;
  const int nwg = gridDim.x;
  const int cpx = nwg / NXCD;
  const int bid = (blockIdx.x % NXCD) * cpx + blockIdx.x / NXCD;
  const int bm = bid / nbn, bn = bid % nbn;

  const int tid = threadIdx.x;
  const int lane = tid & 63;
  const int w = tid >> 6;
  const int wr = w >> 2;
  const int wc = w & 3;

  const int src16 = lane ^ (lane >> 3);
  const int srow0 = w * 8 + (src16 >> 3);
  const int scol  = (src16 & 7) * 16;
  const int8_t* aBase0 = A + (size_t)(bm * BM + srow0) * K + scol;
  const int8_t* aBase1 = A + (size_t)(bm * BM + 128 + srow0) * K + scol;
  const int8_t* bBase0 = B + (size_t)(bn * BN + srow0) * K + scol;
  const int8_t* bBase1 = B + (size_t)(bn * BN + 128 + srow0) * K + scol;
  const size_t jstride = (size_t)64 * K;
  const int dst0 = w * 1024 + lane * 16;

  const int rf = lane & 15;
  const int c0 = ((lane >> 4) * 16) ^ ((lane & 7) << 4);
  const int c1 = (64 + (lane >> 4) * 16) ^ ((lane & 7) << 4);
  const int aRowB = (wr * 16 + rf) * 128;
  const int bRowB = (wc * 16 + rf) * 128;

  i32x4 acc[8][4];
#pragma unroll
  for (int m = 0; m < 8; ++m)
#pragma unroll
    for (int n = 0; n < 4; ++n) acc[m][n] = (i32x4){0, 0, 0, 0};

  i32x4 af[4][2];
  i32x4 bfr[2][2];

  const int NT = K / BK;

  STAGE(aBase0, lds[0] + 0,     0);
  STAGE(bBase0, lds[0] + 32768, 0);
  STAGE(bBase1, lds[0] + 49152, 0);
  STAGE(aBase1, lds[0] + 16384, 0);
  STAGE(aBase0, lds[1] + 0,     BK);
  STAGE(bBase1, lds[1] + 49152, BK);
  asm volatile("s_waitcnt vmcnt(4)" ::: "memory");
  BAR();

  for (int k = 0; k < NT; ++k) {
    char* bufc = lds[k & 1];
    char* bufo = lds[(k & 1) ^ 1];
    const int t1 = (k + 1) * BK, t2 = (k + 2) * BK;
    const bool s1 = (k + 1 < NT), s2 = (k + 2 < NT);

    LDA_HALF(bufc + 0);
    LDB_HALF(bufc + 32768);
    if (s1) STAGE(bBase0, bufo + 32768, t1);
    BAR();
    __builtin_amdgcn_s_setprio(1);
    MMA_QUAD(0, 0);
    __builtin_amdgcn_s_setprio(0);
    BAR();

    LDB_HALF(bufc + 49152);
    if (s1) STAGE(aBase1, bufo + 16384, t1);
    BAR();
    __builtin_amdgcn_s_setprio(1);
    MMA_QUAD(0, 1);
    __builtin_amdgcn_s_setprio(0);
    BAR();

    LDA_HALF(bufc + 16384);
    if (s2) STAGE(aBase0, bufc + 0, t2);
    BAR();
    __builtin_amdgcn_s_setprio(1);
    MMA_QUAD(1, 1);
    __builtin_amdgcn_s_setprio(0);
    BAR();

    LDB_HALF(bufc + 32768);
    if (s2) STAGE(bBase1, bufc + 49152, t2);
    BAR();
    __builtin_amdgcn_s_setprio(1);
    MMA_QUAD(1, 0);
    __builtin_amdgcn_s_setprio(0);
    if (k < NT - 1) {
      if (k <= NT - 3)
        asm volatile("s_waitcnt vmcnt(4)" ::: "memory");
      else
        asm volatile("s_waitcnt vmcnt(0)" ::: "memory");
    }
    BAR();
  }

  const int ch = lane >> 4;
#pragma unroll
  for (int m = 0; m < 8; ++m) {
    const int qm = m >> 2, m4 = m & 3;
#pragma unroll
    for (int n = 0; n < 4; ++n) {
      const int qn = n >> 1, n2 = n & 1;
#pragma unroll
      for (int r = 0; r < 4; ++r) {
        int v = acc[m][n][r];
        C[(size_t)(bm * BM + qm * 128 + m4 * 32 + wr * 16 + ch * 4 + r) * N +
          (bn * BN + qn * 128 + n2 * 64 + wc * 16 + rf)] = (int8_t)((v > 0) - (v < 0));
      }
    }
  }
}

// Last layer: [8192x4096] i8 x [10x4096] i8^T -> sign -> [8192x10] f32.
typedef char i8x16v __attribute__((ext_vector_type(16)));
__global__ __launch_bounds__(256)
void final_layer_i8(const int8_t* __restrict__ A, const int8_t* __restrict__ W,
                    float* __restrict__ out) {
  const int lane = threadIdx.x & 63;
  const int wave = threadIdx.x >> 6;
  const int row = blockIdx.x * 4 + wave;
  const int8_t* a = A + (size_t)row * HID;

  int acc[NCLS];
#pragma unroll
  for (int n = 0; n < NCLS; ++n) acc[n] = 0;

#pragma unroll
  for (int c = 0; c < HID / 1024; ++c) {
    const int k = c * 1024 + lane * 16;
    i8x16v av = *(const i8x16v*)(a + k);
#pragma unroll
    for (int n = 0; n < NCLS; ++n) {
      i8x16v wv = *(const i8x16v*)(W + (size_t)n * HID + k);
      int s = 0;
#pragma unroll
      for (int j = 0; j < 16; ++j) s += (int)av[j] * (int)wv[j];
      acc[n] += s;
    }
  }

#pragma unroll
  for (int n = 0; n < NCLS; ++n) {
    int v = acc[n];
#pragma unroll
    for (int off = 32; off > 0; off >>= 1) v += __shfl_xor(v, off, 64);
    if (lane == 0) out[(size_t)row * NCLS + n] = (float)((v > 0) - (v < 0));
  }
}

extern "C" void kernel_launch(void* const* d_in, const int* in_sizes, int n_in,
                              void* d_out, int out_size, void* d_ws, size_t ws_size,
                              hipStream_t stream) {
  const float* x  = (const float*)d_in[0];
  const float* W0 = (const float*)d_in[1];
  const float* W1 = (const float*)d_in[2];
  const float* W2 = (const float*)d_in[3];
  const float* W3 = (const float*)d_in[4];
  float* out = (float*)d_out;

  // Workspace (~112 MiB): actA 32M | actB 32M | wbuf0/1/2 16M each | w3buf 40K
  char* ws = (char*)d_ws;
  int8_t* actA  = (int8_t*)ws;
  int8_t* actB  = (int8_t*)(ws + (size_t)BATCH * HID);
  int8_t* wb0   = (int8_t*)(ws + (size_t)2 * BATCH * HID);
  int8_t* wb1   = (int8_t*)(ws + (size_t)2 * BATCH * HID + (size_t)HID * HID);
  int8_t* wb2   = (int8_t*)(ws + (size_t)2 * BATCH * HID + (size_t)2 * HID * HID);
  int8_t* w3buf = (int8_t*)(ws + (size_t)2 * BATCH * HID + (size_t)3 * HID * HID);

  const int gemm_grid = (BATCH / 256) * (HID / 256);  // 512, % 8 == 0

  // One fused cast pass: 5245440 chunks of 16 f32 -> 20490 blocks exactly.
  const int total_chunks = 2097152 + 3 * 1048576 + 2560;
  sign_cast_all<<<total_chunks / 256, dim3(256), 0, stream>>>(
      x, W0, W1, W2, W3, actA, wb0, wb1, wb2, w3buf);

  gemm256_i8_sign<<<gemm_grid, dim3(512), 0, stream>>>(actA, wb0, actB, BATCH, HID, INSZ);
  gemm256_i8_sign<<<gemm_grid, dim3(512), 0, stream>>>(actB, wb1, actA, BATCH, HID, HID);
  gemm256_i8_sign<<<gemm_grid, dim3(512), 0, stream>>>(actA, wb2, actB, BATCH, HID, HID);
  final_layer_i8<<<BATCH / 4, dim3(256), 0, stream>>>(actB, w3buf, out);
}